// Round 6
// baseline (356.637 us; speedup 1.0000x reference)
//
#include <hip/hip_runtime.h>

typedef _Float16 f16x8 __attribute__((ext_vector_type(8)));
typedef float f32x4 __attribute__((ext_vector_type(4)));

// Async global->LDS, 16B per lane. LDS dest must be wave-uniform base; HW adds lane*16.
__device__ __forceinline__ void lds_load16(const _Float16* g, _Float16* l) {
    __builtin_amdgcn_global_load_lds(
        (const __attribute__((address_space(1))) void*)g,
        (__attribute__((address_space(3))) void*)l,
        16, 0, 0);
}

// ---------------------------------------------------------------------------
// NT GEMM core: C[M,N] = A[M,K]*B[N,K]^T. fp32 acc, 128xBN tile, BK=32,
// 256 thr (4 waves, 2x2), mfma_f32_16x16x32_f16, double-buffered LDS,
// XCD-aware tile swizzle.
//
// MODE 0 (BN=128): triple projection, z in {0,1,2}. X operand is **f32** and
//   converted during staging (global f32 -> regs -> cvt -> ds_write_b128);
//   W^T operand is f16 via global_load_lds.
//   z=0: q  = Xq@WqT^T + bq[n]   (X=A)   z=1: k likewise
//   z=2: vT = WvT@Xv^T + bv[m]   (X=B, W=A), ldc=8192
// MODE 3 (BN=128): S~ = exp((q k^T)/32) f16 + atomic f32 row sums; z = batch
// MODE 5 (BN=64):  out = (S~ @ v) * (1/rowsum[row]) f32 store; z = batch
// ---------------------------------------------------------------------------
template <int MODE>
__global__ __launch_bounds__(256, MODE == 0 ? 3 : 4)
void gemm_core(const float* X0, const float* X1, const float* X2,
               const _Float16* W0, const _Float16* W1, const _Float16* W2,
               void* C0, void* C1, void* C2,
               const float* b0, const float* b1, const float* b2,
               const _Float16* Af, const _Float16* Bf, void* Cvp, float* rowsum)
{
    constexpr int BN = (MODE == 5) ? 64 : 128;
    constexpr int NJ = BN / 32;           // j-tiles per wave (4 or 2)
    const int z = blockIdx.z;
    const int bx = blockIdx.x, by = blockIdx.y;

    __shared__ __align__(16) _Float16 As[2][128 * 32];
    __shared__ __align__(16) _Float16 Bs[2][BN * 32];

    const int t    = threadIdx.x;
    const int w    = t >> 6;
    const int lane = t & 63;
    const int ln   = lane & 15;
    const int kq   = lane >> 4;
    const int wm   = (w & 1) * 64;
    const int wn   = (w >> 1) * (BN / 2);

    f32x4 acc[4][NJ] = {};

    // ------------------------- MODE 0: projections -------------------------
    if (MODE == 0) {
        const int tmy = bx * 8 + (by >> 3);   // 64-tile side; pins bx -> XCD
        const int tnx = by & 7;
        const float*    Xp = z == 0 ? X0 : z == 1 ? X1 : X2;
        const _Float16* Wp = z == 0 ? W0 : z == 1 ? W1 : W2;
        _Float16*       Cp = (_Float16*)(z == 0 ? C0 : z == 1 ? C1 : C2);
        const float*    bp = z == 0 ? b0 : z == 1 ? b1 : b2;
        const int m0 = (z == 2 ? tnx : tmy) * 128;
        const int n0 = (z == 2 ? tmy : tnx) * 128;
        const int xrow = (z == 2 ? n0 : m0);   // X strip rows
        const int wrow = (z == 2 ? m0 : n0);   // W^T strip rows
        _Float16* bufX[2] = { z == 2 ? Bs[0] : As[0], z == 2 ? Bs[1] : As[1] };
        _Float16* bufW[2] = { z == 2 ? As[0] : Bs[0], z == 2 ? As[1] : Bs[1] };

        // W staging: 128 rows x 64B, 2 lds16/thread (wave-uniform bases).
        const _Float16* gW0 = Wp + (size_t)(wrow + (t >> 2)) * 1024 + (t & 3) * 8;
        const _Float16* gW1 = gW0 + (size_t)64 * 1024;
        // X staging: f32, thread t -> row t>>1, half (t&1): 16 f32 -> 16 halfs.
        const float* gX = Xp + (size_t)(xrow + (t >> 1)) * 1024 + (t & 1) * 16;
        const int xoff = (t >> 1) * 32 + (t & 1) * 16;

        auto stage = [&](int b, int k0) {
            lds_load16(gW0 + k0, bufW[b] + w * 512);
            lds_load16(gW1 + k0, bufW[b] + 2048 + w * 512);
            float4 f0 = *(const float4*)(gX + k0);
            float4 f1 = *(const float4*)(gX + k0 + 4);
            float4 f2 = *(const float4*)(gX + k0 + 8);
            float4 f3 = *(const float4*)(gX + k0 + 12);
            f16x8 h0 = { (_Float16)f0.x, (_Float16)f0.y, (_Float16)f0.z, (_Float16)f0.w,
                         (_Float16)f1.x, (_Float16)f1.y, (_Float16)f1.z, (_Float16)f1.w };
            f16x8 h1 = { (_Float16)f2.x, (_Float16)f2.y, (_Float16)f2.z, (_Float16)f2.w,
                         (_Float16)f3.x, (_Float16)f3.y, (_Float16)f3.z, (_Float16)f3.w };
            *(f16x8*)(bufX[b] + xoff)     = h0;
            *(f16x8*)(bufX[b] + xoff + 8) = h1;
        };

        stage(0, 0);
        int cur = 0;
#pragma unroll 2
        for (int k0 = 0; k0 < 1024; k0 += 32) {
            __syncthreads();
            if (k0 + 32 < 1024) stage(cur ^ 1, k0 + 32);
            const _Float16* Ab = As[cur];
            const _Float16* Bb = Bs[cur];
            f16x8 af[4], bf[4];
#pragma unroll
            for (int i = 0; i < 4; ++i)
                af[i] = *(const f16x8*)(Ab + (wm + i * 16 + ln) * 32 + kq * 8);
#pragma unroll
            for (int i = 0; i < 4; ++i)
                bf[i] = *(const f16x8*)(Bb + (wn + i * 16 + ln) * 32 + kq * 8);
#pragma unroll
            for (int i = 0; i < 4; ++i)
#pragma unroll
                for (int j = 0; j < 4; ++j)
                    acc[i][j] = __builtin_amdgcn_mfma_f32_16x16x32_f16(af[i], bf[j], acc[i][j], 0, 0, 0);
            cur ^= 1;
        }

        const int ldc = (z == 2) ? 8192 : 1024;
#pragma unroll
        for (int i = 0; i < 4; ++i) {
            const int rbase = m0 + wm + i * 16 + kq * 4;
#pragma unroll
            for (int j = 0; j < 4; ++j) {
                const int gcol = n0 + wn + j * 16 + ln;
#pragma unroll
                for (int r = 0; r < 4; ++r) {
                    float vv = acc[i][j][r] + (z == 2 ? bp[rbase + r] : bp[gcol]);
                    Cp[(size_t)(rbase + r) * ldc + gcol] = (_Float16)vv;
                }
            }
        }
        return;
    }

    // --------------------- MODE 3 / MODE 5: f16 x f16 ----------------------
    const int tm = (bx & 7) * 2 + (by >> 3);
    const int tn = (bx >> 3) * 8 + (by & 7);
    const _Float16* A;
    const _Float16* B;
    size_t cbase;
    int lda, ldb, K;
    if (MODE == 3) {
        A = Af + (size_t)z * 2048 * 1024;      // q slice
        B = Bf + (size_t)z * 2048 * 1024;      // k slice
        cbase = (size_t)z * 2048 * 2048;
        lda = 1024; ldb = 1024; K = 1024;
    } else {
        A = Af + (size_t)z * 2048 * 2048;      // S~ slice
        B = Bf + (size_t)z * 2048;             // vT col offset
        cbase = (size_t)z * 2048 * 1024;
        lda = 2048; ldb = 8192; K = 2048;
    }
    rowsum += z * 2048;
    const int m0 = tm * 128;
    const int n0 = tn * BN;

    const _Float16* gA0 = A + (size_t)(m0 + (t >> 2)) * lda + (t & 3) * 8;
    const _Float16* gA1 = gA0 + (size_t)64 * lda;
    const _Float16* gB0 = B + (size_t)(n0 + (t >> 2)) * ldb + (t & 3) * 8;
    const _Float16* gB1 = (BN == 128) ? gB0 + (size_t)64 * ldb : nullptr;

    auto stage = [&](int b, int k0) {
        lds_load16(gA0 + k0, As[b] + w * 512);
        lds_load16(gA1 + k0, As[b] + 2048 + w * 512);
        lds_load16(gB0 + k0, Bs[b] + w * 512);
        if (BN == 128) lds_load16(gB1 + k0, Bs[b] + 2048 + w * 512);
    };

    stage(0, 0);
    int cur = 0;
#pragma unroll 2
    for (int k0 = 0; k0 < K; k0 += 32) {
        __syncthreads();
        if (k0 + 32 < K) stage(cur ^ 1, k0 + 32);
        const _Float16* Ab = As[cur];
        const _Float16* Bb = Bs[cur];
        f16x8 af[4], bf[NJ];
#pragma unroll
        for (int i = 0; i < 4; ++i)
            af[i] = *(const f16x8*)(Ab + (wm + i * 16 + ln) * 32 + kq * 8);
#pragma unroll
        for (int j = 0; j < NJ; ++j)
            bf[j] = *(const f16x8*)(Bb + (wn + j * 16 + ln) * 32 + kq * 8);
#pragma unroll
        for (int i = 0; i < 4; ++i)
#pragma unroll
            for (int j = 0; j < NJ; ++j)
                acc[i][j] = __builtin_amdgcn_mfma_f32_16x16x32_f16(af[i], bf[j], acc[i][j], 0, 0, 0);
        cur ^= 1;
    }

    if (MODE == 3) {
        _Float16* Ch = (_Float16*)Cvp;
#pragma unroll
        for (int i = 0; i < 4; ++i) {
            const int rbase = m0 + wm + i * 16 + kq * 4;
            float rs[4] = {0.f, 0.f, 0.f, 0.f};
#pragma unroll
            for (int j = 0; j < 4; ++j) {
                const int gcol = n0 + wn + j * 16 + ln;
#pragma unroll
                for (int r = 0; r < 4; ++r) {
                    float e = __expf(acc[i][j][r] * 0.03125f);
                    Ch[cbase + (size_t)(rbase + r) * 2048 + gcol] = (_Float16)e;
                    rs[r] += e;
                }
            }
#pragma unroll
            for (int r = 0; r < 4; ++r) {
                float s = rs[r];
                s += __shfl_xor(s, 1);
                s += __shfl_xor(s, 2);
                s += __shfl_xor(s, 4);
                s += __shfl_xor(s, 8);
                if (ln == 0) atomicAdd(&rowsum[rbase + r], s);
            }
        }
    } else {
        float* Cf = (float*)Cvp;
#pragma unroll
        for (int i = 0; i < 4; ++i) {
            const int rbase = m0 + wm + i * 16 + kq * 4;
            float inv[4];
#pragma unroll
            for (int r = 0; r < 4; ++r) inv[r] = 1.f / rowsum[rbase + r];
#pragma unroll
            for (int j = 0; j < NJ; ++j) {
                const int gcol = n0 + wn + j * 16 + ln;
#pragma unroll
                for (int r = 0; r < 4; ++r)
                    Cf[cbase + (size_t)(rbase + r) * 1024 + gcol] = acc[i][j][r] * inv[r];
            }
        }
    }
}

// ---------------------------------------------------------------------------
// Merged 1024x1024 f32 -> f16 transpose x3 (grid.z selects W); also zeros
// rowsum[8192] (z==0, by==0 blocks: 32 blocks x 256 threads).
// ---------------------------------------------------------------------------
__global__ __launch_bounds__(256)
void transpose_w_1024(const float* __restrict__ W0, _Float16* __restrict__ T0,
                      const float* __restrict__ W1, _Float16* __restrict__ T1,
                      const float* __restrict__ W2, _Float16* __restrict__ T2,
                      float* __restrict__ rowsum)
{
    const float* W = blockIdx.z == 0 ? W0 : blockIdx.z == 1 ? W1 : W2;
    _Float16*   WT = blockIdx.z == 0 ? T0 : blockIdx.z == 1 ? T1 : T2;
    __shared__ float tile[32][33];
    const int bx = blockIdx.x * 32;
    const int by = blockIdx.y * 32;
    const int tx = threadIdx.x;
    const int ty = threadIdx.y;
    if (blockIdx.z == 0 && blockIdx.y == 0)
        rowsum[blockIdx.x * 256 + ty * 32 + tx] = 0.f;
#pragma unroll
    for (int i = ty; i < 32; i += 8)
        tile[i][tx] = W[(size_t)(by + i) * 1024 + bx + tx];
    __syncthreads();
#pragma unroll
    for (int i = ty; i < 32; i += 8)
        WT[(size_t)(bx + i) * 1024 + by + tx] = (_Float16)tile[tx][i];
}

// ---------------------------------------------------------------------------
// B=4, Lq=Lk=2048, D=1024.
// transpose(+rowsum zero) -> {q,k,vT} (f32 X staged in-kernel) ->
// S~=exp(qk^T/32)+rowsum -> out = S~@v / rowsum.
// ---------------------------------------------------------------------------
extern "C" void kernel_launch(void* const* d_in, const int* in_sizes, int n_in,
                              void* d_out, int out_size, void* d_ws, size_t ws_size,
                              hipStream_t stream)
{
    const float* Xq = (const float*)d_in[0];
    const float* Xk = (const float*)d_in[1];
    const float* Xv = (const float*)d_in[2];
    const float* Wq = (const float*)d_in[3];
    const float* bq = (const float*)d_in[4];
    const float* Wk = (const float*)d_in[5];
    const float* bk = (const float*)d_in[6];
    const float* Wv = (const float*)d_in[7];
    const float* bv = (const float*)d_in[8];
    float* out = (float*)d_out;

    const size_t XN = (size_t)8192 * 1024;
    const size_t WN = (size_t)1024 * 1024;

    _Float16* ws  = (_Float16*)d_ws;
    _Float16* WqT = ws;
    _Float16* WkT = WqT + WN;
    _Float16* WvT = WkT + WN;
    _Float16* qh  = WvT + WN;
    _Float16* kh  = qh + XN;
    _Float16* vT  = kh + XN;                     // [1024 x 8192]
    _Float16* S   = vT + XN;                     // [4 x 2048 x 2048] (holds exp)
    float* rowsum = (float*)(S + (size_t)4 * 2048 * 2048);   // [8192]

    // 1. transpose weights to f16 W^T + zero rowsum
    {
        dim3 tb(32, 8), tg(32, 32, 3);
        transpose_w_1024<<<tg, tb, 0, stream>>>(Wq, WqT, Wk, WkT, Wv, WvT, rowsum);
    }

    // 2. q, k, vT projections in ONE dispatch (f32 X converted during staging)
    {
        dim3 g(8, 64, 3);
        gemm_core<0><<<g, 256, 0, stream>>>(
            Xq, Xk, Xv, WqT, WkT, WvT, qh, kh, vT, bq, bk, bv,
            nullptr, nullptr, nullptr, nullptr);
    }

    // 3. S~ = exp(q k^T / 32) f16 + atomic f32 row sums
    {
        dim3 g(16, 16, 4);
        gemm_core<3><<<g, 256, 0, stream>>>(
            nullptr, nullptr, nullptr, nullptr, nullptr, nullptr,
            nullptr, nullptr, nullptr, nullptr, nullptr, nullptr,
            qh, kh, S, rowsum);
    }

    // 4. out = (S~ @ v) / rowsum  (128x64 tiles, 1024 blocks = 4/CU)
    {
        dim3 g(16, 16, 4);
        gemm_core<5><<<g, 256, 0, stream>>>(
            nullptr, nullptr, nullptr, nullptr, nullptr, nullptr,
            nullptr, nullptr, nullptr, nullptr, nullptr, nullptr,
            S, vT, out, rowsum);
    }
}

// Round 7
// 327.866 us; speedup vs baseline: 1.0878x; 1.0878x over previous
//
#include <hip/hip_runtime.h>

typedef _Float16 f16x8 __attribute__((ext_vector_type(8)));
typedef _Float16 f16x4 __attribute__((ext_vector_type(4)));
typedef float f32x4 __attribute__((ext_vector_type(4)));

// Async global->LDS, 16B per lane. LDS dest must be wave-uniform base; HW adds lane*16.
__device__ __forceinline__ void lds_load16(const _Float16* g, _Float16* l) {
    __builtin_amdgcn_global_load_lds(
        (const __attribute__((address_space(1))) void*)g,
        (__attribute__((address_space(3))) void*)l,
        16, 0, 0);
}

// ---------------------------------------------------------------------------
// NT GEMM core: C[M,N] = A[M,K]*B[N,K]^T. f16 in, fp32 acc, 128xBN tile,
// BK=32, 256 thr (4 waves, 2x2), mfma_f32_16x16x32_f16, double-buffered LDS
// (1 barrier / K-iter), all-async global_load_lds staging, XCD-aware swizzle.
//
// MODE 0 (BN=128): triple projection, z in {0,1,2}, all-f16 operands:
//   z=0: q  = Xqh@WqT^T + bq[n]   z=1: k = Xkh@WkT^T + bk[n]   (ldc=1024)
//   z=2: vT = WvT@Xvh^T + bv[m]   (ldc=8192)
// MODE 3 (BN=128): S~ = exp((q k^T)/32) f16 + atomic f32 row sums; z = batch
// MODE 5 (BN=64):  out = (S~ @ v) * (1/rowsum[row]) f32 store; z = batch
// ---------------------------------------------------------------------------
template <int MODE>
__global__ __launch_bounds__(256, 4)
void gemm_core(const _Float16* A0, const _Float16* B0, void* C0, const float* b0,
               const _Float16* A1, const _Float16* B1, void* C1, const float* b1,
               const _Float16* A2, const _Float16* B2, void* C2, const float* b2,
               float* rowsum)
{
    constexpr int BN = (MODE == 5) ? 64 : 128;
    constexpr int NJ = BN / 32;           // j-tiles per wave (4 or 2)
    const int z = blockIdx.z;
    const int bx = blockIdx.x, by = blockIdx.y;

    __shared__ __align__(16) _Float16 As[2][128 * 32];
    __shared__ __align__(16) _Float16 Bs[2][BN * 32];

    const int t    = threadIdx.x;
    const int w    = t >> 6;
    const int lane = t & 63;
    const int ln   = lane & 15;
    const int kq   = lane >> 4;
    const int wm   = (w & 1) * 64;
    const int wn   = (w >> 1) * (BN / 2);

    const _Float16* A;
    const _Float16* B;
    size_t cbase = 0;
    int lda, ldb, K, m0, n0;

    if (MODE == 0) {
        // grid (8,64,3); XCD = bx (pins the 64-long tile side -> one XCD/strip).
        const int tmy = bx * 8 + (by >> 3);
        const int tnx = by & 7;
        A = z == 0 ? A0 : z == 1 ? A1 : A2;
        B = z == 0 ? B0 : z == 1 ? B1 : B2;
        lda = 1024; ldb = 1024; K = 1024;
        m0 = (z == 2 ? tnx : tmy) * 128;
        n0 = (z == 2 ? tmy : tnx) * 128;
    } else if (MODE == 3) {
        // grid (16,16,4); XCD = bx&7 (pins tm pair).
        const int tm = (bx & 7) * 2 + (by >> 3);
        const int tn = (bx >> 3) * 8 + (by & 7);
        A = A0 + (size_t)z * 2048 * 1024;      // q slice
        B = B0 + (size_t)z * 2048 * 1024;      // k slice
        cbase = (size_t)z * 2048 * 2048;
        rowsum += z * 2048;
        lda = 1024; ldb = 1024; K = 1024;
        m0 = tm * 128; n0 = tn * 128;
    } else {
        // grid (16,16,4); tiles 128x64; XCD = bx&7.
        const int tm = (bx & 7) * 2 + (by >> 3);
        const int tn = (bx >> 3) * 8 + (by & 7);
        A = A0 + (size_t)z * 2048 * 2048;      // S~ slice
        B = B0 + (size_t)z * 2048;             // vT col offset
        cbase = (size_t)z * 2048 * 1024;
        rowsum += z * 2048;
        lda = 2048; ldb = 8192; K = 2048;
        m0 = tm * 128; n0 = tn * BN;
    }

    // Staging: rows x 64B, 16B chunks in lane order (contiguous LDS dest).
    const _Float16* gA0 = A + (size_t)(m0 + (t >> 2)) * lda + (t & 3) * 8;
    const _Float16* gA1 = gA0 + (size_t)64 * lda;
    const _Float16* gB0 = B + (size_t)(n0 + (t >> 2)) * ldb + (t & 3) * 8;
    const _Float16* gB1 = (BN == 128) ? gB0 + (size_t)64 * ldb : nullptr;

    auto stage = [&](int b, int k0) {
        lds_load16(gA0 + k0, As[b] + w * 512);
        lds_load16(gA1 + k0, As[b] + 2048 + w * 512);
        lds_load16(gB0 + k0, Bs[b] + w * 512);
        if (BN == 128) lds_load16(gB1 + k0, Bs[b] + 2048 + w * 512);
    };

    f32x4 acc[4][NJ] = {};

    stage(0, 0);
    int cur = 0;
#pragma unroll 2
    for (int k0 = 0; k0 < K; k0 += 32) {
        __syncthreads();               // drains cur-buf loads (issued 1 phase ago)
        if (k0 + 32 < K) stage(cur ^ 1, k0 + 32);
        const _Float16* Ab = As[cur];
        const _Float16* Bb = Bs[cur];
        f16x8 af[4], bf[NJ];
#pragma unroll
        for (int i = 0; i < 4; ++i)
            af[i] = *(const f16x8*)(Ab + (wm + i * 16 + ln) * 32 + kq * 8);
#pragma unroll
        for (int j = 0; j < NJ; ++j)
            bf[j] = *(const f16x8*)(Bb + (wn + j * 16 + ln) * 32 + kq * 8);
#pragma unroll
        for (int i = 0; i < 4; ++i)
#pragma unroll
            for (int j = 0; j < NJ; ++j)
                acc[i][j] = __builtin_amdgcn_mfma_f32_16x16x32_f16(af[i], bf[j], acc[i][j], 0, 0, 0);
        cur ^= 1;
    }

    // Epilogue. C/D layout: col = lane&15, row = (lane>>4)*4 + reg.
    if (MODE == 0) {
        _Float16* Cp = (_Float16*)(z == 0 ? C0 : z == 1 ? C1 : C2);
        const float* bp = z == 0 ? b0 : z == 1 ? b1 : b2;
        const int ldc = (z == 2) ? 8192 : 1024;
#pragma unroll
        for (int i = 0; i < 4; ++i) {
            const int rbase = m0 + wm + i * 16 + kq * 4;
#pragma unroll
            for (int j = 0; j < 4; ++j) {
                const int gcol = n0 + wn + j * 16 + ln;
#pragma unroll
                for (int r = 0; r < 4; ++r) {
                    float vv = acc[i][j][r] + (z == 2 ? bp[rbase + r] : bp[gcol]);
                    Cp[(size_t)(rbase + r) * ldc + gcol] = (_Float16)vv;
                }
            }
        }
    } else if (MODE == 3) {
        _Float16* Ch = (_Float16*)C0;
#pragma unroll
        for (int i = 0; i < 4; ++i) {
            const int rbase = m0 + wm + i * 16 + kq * 4;
            float rs[4] = {0.f, 0.f, 0.f, 0.f};
#pragma unroll
            for (int j = 0; j < 4; ++j) {
                const int gcol = n0 + wn + j * 16 + ln;
#pragma unroll
                for (int r = 0; r < 4; ++r) {
                    float e = __expf(acc[i][j][r] * 0.03125f);
                    Ch[cbase + (size_t)(rbase + r) * 2048 + gcol] = (_Float16)e;
                    rs[r] += e;
                }
            }
#pragma unroll
            for (int r = 0; r < 4; ++r) {
                float s = rs[r];
                s += __shfl_xor(s, 1);
                s += __shfl_xor(s, 2);
                s += __shfl_xor(s, 4);
                s += __shfl_xor(s, 8);
                if (ln == 0) atomicAdd(&rowsum[rbase + r], s);
            }
        }
    } else {
        float* Cf = (float*)C0;
#pragma unroll
        for (int i = 0; i < 4; ++i) {
            const int rbase = m0 + wm + i * 16 + kq * 4;
            float inv[4];
#pragma unroll
            for (int r = 0; r < 4; ++r) inv[r] = 1.f / rowsum[rbase + r];
#pragma unroll
            for (int j = 0; j < NJ; ++j) {
                const int gcol = n0 + wn + j * 16 + ln;
#pragma unroll
                for (int r = 0; r < 4; ++r)
                    Cf[cbase + (size_t)(rbase + r) * 1024 + gcol] = acc[i][j][r] * inv[r];
            }
        }
    }
}

// ---------------------------------------------------------------------------
// Prep kernel, ONE launch. grid (8192, 4), 256 threads:
//   y in {0,1,2}: f32->f16 convert of X_y (float4/thread); y==0,x<32 zeros rowsum.
//   y==3, x<3072: 32x32 transpose tile of W_{x/1024} -> f16 W^T.
// ---------------------------------------------------------------------------
__global__ __launch_bounds__(256)
void prep(const float4* __restrict__ x0, _Float16* __restrict__ y0,
          const float4* __restrict__ x1, _Float16* __restrict__ y1,
          const float4* __restrict__ x2, _Float16* __restrict__ y2,
          const float* __restrict__ W0, _Float16* __restrict__ T0,
          const float* __restrict__ W1, _Float16* __restrict__ T1,
          const float* __restrict__ W2, _Float16* __restrict__ T2,
          float* __restrict__ rowsum)
{
    if (blockIdx.y < 3) {
        const size_t i = (size_t)blockIdx.x * 256 + threadIdx.x;
        const float4* x = blockIdx.y == 0 ? x0 : blockIdx.y == 1 ? x1 : x2;
        _Float16*    yy = blockIdx.y == 0 ? y0 : blockIdx.y == 1 ? y1 : y2;
        float4 f = x[i];
        f16x4 o = { (_Float16)f.x, (_Float16)f.y, (_Float16)f.z, (_Float16)f.w };
        *(f16x4*)(yy + i * 4) = o;
        if (blockIdx.y == 0 && blockIdx.x < 32)
            rowsum[blockIdx.x * 256 + threadIdx.x] = 0.f;
        return;
    }
    if (blockIdx.x >= 3072) return;
    const int zz = blockIdx.x >> 10;          // which W
    const int tb = blockIdx.x & 1023;         // tile id: 32x32 grid of 32x32 tiles
    const float* W = zz == 0 ? W0 : zz == 1 ? W1 : W2;
    _Float16*   WT = zz == 0 ? T0 : zz == 1 ? T1 : T2;
    __shared__ float tile[32][33];
    const int bxs = (tb & 31) * 32;           // source col block
    const int bys = (tb >> 5) * 32;           // source row block
    const int tx = threadIdx.x & 31;
    const int ty = threadIdx.x >> 5;          // 0..7
#pragma unroll
    for (int i = ty; i < 32; i += 8)
        tile[i][tx] = W[(size_t)(bys + i) * 1024 + bxs + tx];
    __syncthreads();
#pragma unroll
    for (int i = ty; i < 32; i += 8)
        WT[(size_t)(bxs + i) * 1024 + bys + tx] = (_Float16)tile[tx][i];
}

// ---------------------------------------------------------------------------
// B=4, Lq=Lk=2048, D=1024.
// prep (cvt+transpose+zero) -> {q,k,vT} one dispatch -> S~=exp(qk^T/32)+rowsum
// -> out = S~@v / rowsum.
// ---------------------------------------------------------------------------
extern "C" void kernel_launch(void* const* d_in, const int* in_sizes, int n_in,
                              void* d_out, int out_size, void* d_ws, size_t ws_size,
                              hipStream_t stream)
{
    const float* Xq = (const float*)d_in[0];
    const float* Xk = (const float*)d_in[1];
    const float* Xv = (const float*)d_in[2];
    const float* Wq = (const float*)d_in[3];
    const float* bq = (const float*)d_in[4];
    const float* Wk = (const float*)d_in[5];
    const float* bk = (const float*)d_in[6];
    const float* Wv = (const float*)d_in[7];
    const float* bv = (const float*)d_in[8];
    float* out = (float*)d_out;

    const size_t XN = (size_t)8192 * 1024;
    const size_t WN = (size_t)1024 * 1024;

    _Float16* ws  = (_Float16*)d_ws;
    _Float16* Xqh = ws;
    _Float16* Xkh = Xqh + XN;
    _Float16* Xvh = Xkh + XN;
    _Float16* WqT = Xvh + XN;
    _Float16* WkT = WqT + WN;
    _Float16* WvT = WkT + WN;
    _Float16* qh  = WvT + WN;
    _Float16* kh  = qh + XN;
    _Float16* vT  = kh + XN;                     // [1024 x 8192]
    _Float16* S   = vT + XN;                     // [4 x 2048 x 2048] (holds exp)
    float* rowsum = (float*)(S + (size_t)4 * 2048 * 2048);   // [8192]

    // 1. prep: convert X to f16, transpose W to f16 W^T, zero rowsum
    {
        dim3 g(8192, 4);
        prep<<<g, 256, 0, stream>>>((const float4*)Xq, Xqh,
                                    (const float4*)Xk, Xkh,
                                    (const float4*)Xv, Xvh,
                                    Wq, WqT, Wk, WkT, Wv, WvT, rowsum);
    }

    // 2. q, k, vT projections in ONE dispatch (1536 blocks)
    {
        dim3 g(8, 64, 3);
        gemm_core<0><<<g, 256, 0, stream>>>(
            Xqh, WqT, qh, bq,
            Xkh, WkT, kh, bk,
            WvT, Xvh, vT, bv,
            nullptr);
    }

    // 3. S~ = exp(q k^T / 32) f16 + atomic f32 row sums (1024 blocks)
    {
        dim3 g(16, 16, 4);
        gemm_core<3><<<g, 256, 0, stream>>>(
            qh, kh, S, nullptr,
            nullptr, nullptr, nullptr, nullptr,
            nullptr, nullptr, nullptr, nullptr,
            rowsum);
    }

    // 4. out = (S~ @ v) / rowsum  (128x64 tiles, 1024 blocks)
    {
        dim3 g(16, 16, 4);
        gemm_core<5><<<g, 256, 0, stream>>>(
            S, vT, out, nullptr,
            nullptr, nullptr, nullptr, nullptr,
            nullptr, nullptr, nullptr, nullptr,
            rowsum);
    }
}